// Round 3
// baseline (208.585 us; speedup 1.0000x reference)
//
#include <hip/hip_runtime.h>

// Problem constants
#define BB_   16
#define CIN_  32
#define COUT_ 64
#define TT_   20      // depthwise time extent
#define NSTEP 22      // recurrence steps (pointwise pad grows T 20->22)
#define NPIX  1024    // 32*32
#define HW_   32

typedef float floatx4 __attribute__((ext_vector_type(4)));

// ws layout (in floats)
#define N_DWOUT (10485760ULL)                  // 16*32*20*1024
#define OFF_DWOUT 0ULL
#define OFF_D     (OFF_DWOUT + N_DWOUT)        // 4096 floats
#define OFF_INVN  (OFF_D + 4096ULL)            // 64 floats
#define OFF_CNT   (OFF_INVN + 64ULL)           // 22 uint32
#define WS_FLOATS (OFF_CNT + 32ULL)

// ---------------------------------------------------------------------------
// K1: depthwise 3x3x3 conv, per (b, ci, t-quarter). dwout[b][ci][t][h][w]
// ---------------------------------------------------------------------------
__global__ __launch_bounds__(128)
void k_depthwise(const float* __restrict__ x, const float* __restrict__ wdw,
                 float* __restrict__ dwout) {
    const int blk = blockIdx.x;
    const int t4 = blk & 3;
    const int ci = (blk >> 2) & 31;
    const int b  = blk >> 7;
    const int tid = threadIdx.x;
    __shared__ float pl[3][34][35];

    float w[27];
#pragma unroll
    for (int k = 0; k < 27; ++k) w[k] = wdw[ci * 27 + k];

    for (int i = tid; i < 3 * 34 * 35; i += 128) (&pl[0][0][0])[i] = 0.f;
    __syncthreads();

    const float* xb = x + (size_t)(b * 32 + ci) * TT_ * NPIX;
    const int lr = tid >> 2;            // 0..31 row
    const int lc = (tid & 3) * 8;       // col group of 8

    auto load_plane = [&](int p, int slot) {
        const float* s = xb + (size_t)p * NPIX + lr * 32 + lc;
        float4 v0 = *(const float4*)s;
        float4 v1 = *(const float4*)(s + 4);
        float* d = &pl[slot][1 + lr][1 + lc];
        d[0] = v0.x; d[1] = v0.y; d[2] = v0.z; d[3] = v0.w;
        d[4] = v1.x; d[5] = v1.y; d[6] = v1.z; d[7] = v1.w;
    };
    auto zero_plane = [&](int slot) {
        float* d = &pl[slot][1 + lr][1 + lc];
#pragma unroll
        for (int j = 0; j < 8; ++j) d[j] = 0.f;
    };

    const int T0 = t4 * 5;
    if (T0 > 0) load_plane(T0 - 1, (T0 - 1) % 3);
    load_plane(T0, T0 % 3);

    const int hd = lr, wd0 = lc;
    const float* base = &pl[0][0][0];

    for (int t = T0; t < T0 + 5; ++t) {
        __syncthreads();
        const int pnext = t + 1;
        if (pnext < TT_) load_plane(pnext, pnext % 3);
        else             zero_plane(pnext % 3);
        __syncthreads();

        const int sm1 = (t + 2) % 3, s0 = t % 3, sp1 = (t + 1) % 3;
        float acc[8] = {0.f,0.f,0.f,0.f,0.f,0.f,0.f,0.f};
#pragma unroll
        for (int kt = 0; kt < 3; ++kt) {
            const int slot = (kt == 0) ? sm1 : (kt == 1) ? s0 : sp1;
            const float* Pp = base + slot * (34 * 35);
#pragma unroll
            for (int kh = 0; kh < 3; ++kh) {
                const float* row = Pp + (hd + kh) * 35 + wd0;
                float r[10];
#pragma unroll
                for (int m = 0; m < 10; ++m) r[m] = row[m];
#pragma unroll
                for (int kw = 0; kw < 3; ++kw) {
                    const float wv = w[(kt * 3 + kh) * 3 + kw];
#pragma unroll
                    for (int j = 0; j < 8; ++j) acc[j] = fmaf(wv, r[j + kw], acc[j]);
                }
            }
        }
        float* dst = dwout + ((size_t)(b * 32 + ci) * TT_ + t) * NPIX + hd * 32 + wd0;
        *(float4*)dst       = make_float4(acc[0], acc[1], acc[2], acc[3]);
        *(float4*)(dst + 4) = make_float4(acc[4], acc[5], acc[6], acc[7]);
    }
}

// ---------------------------------------------------------------------------
// K2: lateral matrix d = Wpw diag(S) Wpw^T (fp64), inv_norm; also zeros gcnt
// ---------------------------------------------------------------------------
__global__ __launch_bounds__(256)
void k_dmat(const float* __restrict__ wdw, const float* __restrict__ wpw,
            float* __restrict__ dmat, float* __restrict__ invn,
            unsigned* __restrict__ gcnt) {
    __shared__ double S[32];
    const int tid = threadIdx.x;
    if (tid < NSTEP) gcnt[tid] = 0u;
    if (tid < 32) {
        double s = 0.0;
        for (int k = 0; k < 27; ++k) { double v = (double)wdw[tid * 27 + k]; s += v * v; }
        S[tid] = s;
    }
    __syncthreads();
    for (int e = tid; e < 4096; e += 256) {
        const int a = e >> 6, f = e & 63;
        double acc = 0.0;
        for (int ci = 0; ci < 32; ++ci)
            acc += (double)wpw[a * 32 + ci] * (double)wpw[f * 32 + ci] * S[ci];
        dmat[e] = (float)acc;
        if (a == f) invn[a] = (float)(1.0 / (acc + 1e-8));
    }
}

// ---------------------------------------------------------------------------
// K3: fused pointwise conv + leaky soft-reset recurrence.
// block = (b, h, w-half): 1024 blocks -> 4 resident/CU. thread = 2co x 2w.
// Per step: stage shifted row dwout[b,:,t-1,h-1,:] in LDS (double-buffered,
// global prefetch 1 step ahead); inp = sum_ci wpw*dwin (ci-ascending fmaf,
// bit-identical to unfused GEMM). Spike masks + step counter double-buffered
// by t-parity -> 2 barriers/step. Lateral reset couples only within a pixel,
// so the w-split is exact.
// ---------------------------------------------------------------------------
__global__ __launch_bounds__(256, 4)
void k_recur_fused(const float* __restrict__ dwout, const float* __restrict__ wpw,
                   const float* __restrict__ dmat, const float* __restrict__ invn_g,
                   const float* __restrict__ beta_g, const float* __restrict__ bvec,
                   float* __restrict__ out, unsigned* __restrict__ gcnt) {
    const int blk = blockIdx.x;
    const int wh = blk & 1;
    const int h  = (blk >> 1) & 31;
    const int b  = blk >> 6;
    const int tid = threadIdx.x;
    const int cp = tid >> 3;          // 0..31 co-pair
    const int wq = tid & 7;           // 0..7
    const int co0 = cp * 2;
    const int wl0 = wq * 2;           // local pixel (0..14, even)
    const int wg0 = wh * 16 + wl0;    // global w of pixel 0

    __shared__ __align__(16) float d_lds[4096];
    __shared__ __align__(16) float dwin[2][32][40];   // [buf][ci][1+w]; [0]=left pad
    __shared__ unsigned msk[2][2][16];                // [slot][lo/hi][pix]
    __shared__ unsigned cnt_sh[2];

    for (int i = tid; i < 4096; i += 256) d_lds[i] = dmat[i];
    {
        float* p = &dwin[0][0][0];
        for (int i = tid; i < 2 * 32 * 40; i += 256) p[i] = 0.f;
    }
    if (tid < 64) (&msk[0][0][0])[tid] = 0u;
    if (tid < 2) cnt_sh[tid] = 0u;

    const float beta_v = beta_g[0];
    const float omb = 1.0f - beta_v;
    const float invn0 = invn_g[co0], invn1 = invn_g[co0 + 1];
    const float bth0 = bvec[co0],    bth1 = bvec[co0 + 1];

    // wpw rows for this thread's two channels (64 VGPRs)
    float2 wa[32];
#pragma unroll
    for (int ci = 0; ci < 32; ++ci)
        wa[ci] = make_float2(wpw[co0 * 32 + ci], wpw[(co0 + 1) * 32 + ci]);

    float mem0[2] = {0.f, 0.f}, mem1[2] = {0.f, 0.f};

    // t = 0: inp = 0 (time pad) -> mem 0 -> mthr = -b < 0 -> spikes all zero.
    const size_t ob0 = ((size_t)(b * 64 + co0) * NSTEP) * NPIX + h * 32 + wg0;
    const size_t ob1 = ob0 + (size_t)NSTEP * NPIX;
    *(float2*)(out + ob0) = make_float2(0.f, 0.f);
    *(float2*)(out + ob1) = make_float2(0.f, 0.f);

    const int sci = tid >> 3, seg = tid & 7;   // staging role: ci row, float4 segment
    const float* srow = dwout + ((size_t)(b * 32 + sci) * TT_) * NPIX + (h - 1) * 32;
    const bool hok = (h >= 1);

    __syncthreads();                  // zero-init visible before staging writes

    if (hok) {                        // stage plane 0 (for t=1) into dwin[1]
        float4 g = *(const float4*)(srow + seg * 4);
        float* dp = &dwin[1][sci][1 + seg * 4];
        dp[0] = g.x; dp[1] = g.y; dp[2] = g.z; dp[3] = g.w;
    }
    __syncthreads();

    for (int t = 1; t < NSTEP; ++t) {
        const int wr = t & 1, rd = wr ^ 1;   // mask slots: read rd (t-1 spikes), write wr
        const int cur = t & 1;               // dwin buffer for this step

        // deferred per-step spike accounting for t-1 (slot rd complete since B2)
        if (tid == 0) {
            const unsigned c = cnt_sh[rd];
            if (c) atomicAdd(&gcnt[t - 1], c);
            cnt_sh[rd] = 0u;
        }

        // prefetch next row (plane t, for step t+1)
        float4 gn;
        const bool pf = hok && (t <= TT_ - 1);
        if (pf) gn = *(const float4*)(srow + (size_t)t * NPIX + seg * 4);

        // lateral reset from previous step's spikes (sparse bit iteration)
        float rst0[2], rst1[2];
#pragma unroll
        for (int p = 0; p < 2; ++p) {
            float r0 = 0.f, r1 = 0.f;
            unsigned m0 = msk[rd][0][wl0 + p], m1 = msk[rd][1][wl0 + p];
            while (m0) { const int a = __builtin_ctz(m0); m0 &= m0 - 1;
                const float2 dv = *(const float2*)&d_lds[(a << 6) + co0]; r0 += dv.x; r1 += dv.y; }
            while (m1) { const int a = __builtin_ctz(m1); m1 &= m1 - 1;
                const float2 dv = *(const float2*)&d_lds[((a + 32) << 6) + co0]; r0 += dv.x; r1 += dv.y; }
            rst0[p] = r0; rst1[p] = r1;
        }

        // pointwise conv input (fused; ci-ascending fmaf chain, bit-exact)
        float inp0[2] = {0.f, 0.f}, inp1[2] = {0.f, 0.f};
        if (t <= TT_) {
#pragma unroll
            for (int ci = 0; ci < 32; ++ci) {
                const float2 bv = *(const float2*)&dwin[cur][ci][wg0];  // idx w = 1+(w-1)
                const float ax = wa[ci].x, ay = wa[ci].y;
                inp0[0] = fmaf(ax, bv.x, inp0[0]); inp0[1] = fmaf(ax, bv.y, inp0[1]);
                inp1[0] = fmaf(ay, bv.x, inp1[0]); inp1[1] = fmaf(ay, bv.y, inp1[1]);
            }
        }

        // membrane update + spike (same op order as validated round-2 pass)
        unsigned cnt = 0;
        float spk0[2], spk1[2];
#pragma unroll
        for (int p = 0; p < 2; ++p) {
            const float u0 = (mem0[p] - rst0[p]) * beta_v;
            mem0[p] = u0 + inp0[p] * omb;
            const bool s0 = (mem0[p] * invn0 - bth0) > 0.f;
            spk0[p] = s0 ? 1.f : 0.f; cnt += s0 ? 1u : 0u;
            const float u1 = (mem1[p] - rst1[p]) * beta_v;
            mem1[p] = u1 + inp1[p] * omb;
            const bool s1 = (mem1[p] * invn1 - bth1) > 0.f;
            spk1[p] = s1 ? 1.f : 0.f; cnt += s1 ? 1u : 0u;
        }
        *(float2*)(out + ob0 + (size_t)t * NPIX) = make_float2(spk0[0], spk0[1]);
        *(float2*)(out + ob1 + (size_t)t * NPIX) = make_float2(spk1[0], spk1[1]);

        __syncthreads();              // B1: msk[rd] + dwin[cur] reads complete
        if (pf) {                     // stage prefetched row into other dwin buffer
            float* dp = &dwin[cur ^ 1][sci][1 + seg * 4];
            dp[0] = gn.x; dp[1] = gn.y; dp[2] = gn.z; dp[3] = gn.w;
        }
        if (tid < 32) msk[rd][tid >> 4][tid & 15] = 0u;   // zero read-slot for t+1's writes
        if (cnt) {
#pragma unroll
            for (int p = 0; p < 2; ++p) {
                const unsigned bits = (spk0[p] > 0.f ? 1u : 0u) | (spk1[p] > 0.f ? 2u : 0u);
                if (bits) atomicOr(&msk[wr][cp >> 4][wl0 + p], bits << (co0 & 31));
            }
            atomicAdd(&cnt_sh[wr], cnt);
        }
        __syncthreads();              // B2: masks + staged dwin ready for t+1
    }
    // flush final step's count (slot (NSTEP-1)&1 complete after last B2)
    if (tid == 0) {
        const unsigned c = cnt_sh[(NSTEP - 1) & 1];
        if (c) atomicAdd(&gcnt[NSTEP - 1], c);
    }
}

// ---------------------------------------------------------------------------
// K4: losses from exact integer spike counts
// ---------------------------------------------------------------------------
__global__ void k_final(const unsigned* __restrict__ gcnt, float* __restrict__ out,
                        int out_size) {
    if (threadIdx.x == 0 && blockIdx.x == 0) {
        unsigned long long tot = 0; unsigned mx = 0;
        for (int t = 0; t < NSTEP; ++t) { const unsigned c = gcnt[t]; tot += c; if (c > mx) mx = c; }
        const long long nspk = (long long)out_size - 2;          // 23,068,672
        out[out_size - 2] = (float)(0.5 * ((double)tot / (double)nspk));
        out[out_size - 1] = (float)((double)mx / 1048576.0);     // / (B*COUT*H*W)
    }
}

extern "C" void kernel_launch(void* const* d_in, const int* in_sizes, int n_in,
                              void* d_out, int out_size, void* d_ws, size_t ws_size,
                              hipStream_t stream) {
    const float* x    = (const float*)d_in[0];
    const float* wdw  = (const float*)d_in[1];
    const float* wpw  = (const float*)d_in[2];
    const float* beta = (const float*)d_in[3];
    const float* bvec = (const float*)d_in[4];
    float* out = (float*)d_out;
    float* ws  = (float*)d_ws;

    if (ws_size < WS_FLOATS * sizeof(float)) return;

    float* dwout = ws + OFF_DWOUT;
    float* dmat  = ws + OFF_D;
    float* invn  = ws + OFF_INVN;
    unsigned* gcnt = (unsigned*)(ws + OFF_CNT);

    k_dmat       <<<1, 256, 0, stream>>>(wdw, wpw, dmat, invn, gcnt);   // tiny, first
    k_depthwise  <<<BB_ * CIN_ * 4, 128, 0, stream>>>(x, wdw, dwout);
    k_recur_fused<<<BB_ * HW_ * 2, 256, 0, stream>>>(dwout, wpw, dmat, invn, beta, bvec, out, gcnt);
    k_final      <<<1, 64, 0, stream>>>(gcnt, out, out_size);
}

// Round 4
// 99.386 us; speedup vs baseline: 2.0987x; 2.0987x over previous
//
#include <hip/hip_runtime.h>

// Problem constants
#define BB_   16
#define CIN_  32
#define COUT_ 64
#define TT_   20      // depthwise time extent
#define NSTEP 22      // recurrence steps (pointwise pad grows T 20->22)
#define NPIX  1024    // 32*32
#define HW_   32

typedef float f32x16 __attribute__((ext_vector_type(16)));

// ws layout (in floats)
#define N_DWOUT 10485760ULL                    // 16*32*20*1024 [ci-major]
#define N_DW2   10485760ULL                    // 16*20*32*1024 [slot][ci] transposed
#define OFF_DWOUT 0ULL
#define OFF_DW2   (OFF_DWOUT + N_DWOUT)
#define OFF_D     (OFF_DW2 + N_DW2)            // 4096 floats
#define OFF_INVN  (OFF_D + 4096ULL)            // 64 floats
#define OFF_CNT   (OFF_INVN + 64ULL)           // 22 uint32
#define WS_FLOATS (OFF_CNT + 32ULL)

// ---------------------------------------------------------------------------
// K1: depthwise 3x3x3 conv (unchanged, validated). dwout[b][ci][t][h][w]
// ---------------------------------------------------------------------------
__global__ __launch_bounds__(128)
void k_depthwise(const float* __restrict__ x, const float* __restrict__ wdw,
                 float* __restrict__ dwout) {
    const int blk = blockIdx.x;
    const int t4 = blk & 3;
    const int ci = (blk >> 2) & 31;
    const int b  = blk >> 7;
    const int tid = threadIdx.x;
    __shared__ float pl[3][34][35];

    float w[27];
#pragma unroll
    for (int k = 0; k < 27; ++k) w[k] = wdw[ci * 27 + k];

    for (int i = tid; i < 3 * 34 * 35; i += 128) (&pl[0][0][0])[i] = 0.f;
    __syncthreads();

    const float* xb = x + (size_t)(b * 32 + ci) * TT_ * NPIX;
    const int lr = tid >> 2;
    const int lc = (tid & 3) * 8;

    auto load_plane = [&](int p, int slot) {
        const float* s = xb + (size_t)p * NPIX + lr * 32 + lc;
        float4 v0 = *(const float4*)s;
        float4 v1 = *(const float4*)(s + 4);
        float* d = &pl[slot][1 + lr][1 + lc];
        d[0] = v0.x; d[1] = v0.y; d[2] = v0.z; d[3] = v0.w;
        d[4] = v1.x; d[5] = v1.y; d[6] = v1.z; d[7] = v1.w;
    };
    auto zero_plane = [&](int slot) {
        float* d = &pl[slot][1 + lr][1 + lc];
#pragma unroll
        for (int j = 0; j < 8; ++j) d[j] = 0.f;
    };

    const int T0 = t4 * 5;
    if (T0 > 0) load_plane(T0 - 1, (T0 - 1) % 3);
    load_plane(T0, T0 % 3);

    const int hd = lr, wd0 = lc;
    const float* base = &pl[0][0][0];

    for (int t = T0; t < T0 + 5; ++t) {
        __syncthreads();
        const int pnext = t + 1;
        if (pnext < TT_) load_plane(pnext, pnext % 3);
        else             zero_plane(pnext % 3);
        __syncthreads();

        const int sm1 = (t + 2) % 3, s0 = t % 3, sp1 = (t + 1) % 3;
        float acc[8] = {0.f,0.f,0.f,0.f,0.f,0.f,0.f,0.f};
#pragma unroll
        for (int kt = 0; kt < 3; ++kt) {
            const int slot = (kt == 0) ? sm1 : (kt == 1) ? s0 : sp1;
            const float* Pp = base + slot * (34 * 35);
#pragma unroll
            for (int kh = 0; kh < 3; ++kh) {
                const float* row = Pp + (hd + kh) * 35 + wd0;
                float r[10];
#pragma unroll
                for (int m = 0; m < 10; ++m) r[m] = row[m];
#pragma unroll
                for (int kw = 0; kw < 3; ++kw) {
                    const float wv = w[(kt * 3 + kh) * 3 + kw];
#pragma unroll
                    for (int j = 0; j < 8; ++j) acc[j] = fmaf(wv, r[j + kw], acc[j]);
                }
            }
        }
        float* dst = dwout + ((size_t)(b * 32 + ci) * TT_ + t) * NPIX + hd * 32 + wd0;
        *(float4*)dst       = make_float4(acc[0], acc[1], acc[2], acc[3]);
        *(float4*)(dst + 4) = make_float4(acc[4], acc[5], acc[6], acc[7]);
    }
}

// ---------------------------------------------------------------------------
// K2: lateral matrix d (fp64), inv_norm; zeros gcnt. Unchanged.
// ---------------------------------------------------------------------------
__global__ __launch_bounds__(256)
void k_dmat(const float* __restrict__ wdw, const float* __restrict__ wpw,
            float* __restrict__ dmat, float* __restrict__ invn,
            unsigned* __restrict__ gcnt) {
    __shared__ double S[32];
    const int tid = threadIdx.x;
    if (tid < NSTEP) gcnt[tid] = 0u;
    if (tid < 32) {
        double s = 0.0;
        for (int k = 0; k < 27; ++k) { double v = (double)wdw[tid * 27 + k]; s += v * v; }
        S[tid] = s;
    }
    __syncthreads();
    for (int e = tid; e < 4096; e += 256) {
        const int a = e >> 6, f = e & 63;
        double acc = 0.0;
        for (int ci = 0; ci < 32; ++ci)
            acc += (double)wpw[a * 32 + ci] * (double)wpw[f * 32 + ci] * S[ci];
        dmat[e] = (float)acc;
        if (a == f) invn[a] = (float)(1.0 / (acc + 1e-8));
    }
}

// ---------------------------------------------------------------------------
// K2b: transpose dwout [b][ci][t][h][w] -> dw2 [b][t][h][slot=w+1][ci],
// slot 0 = zeros (built-in left w-pad). Coalesced both sides via LDS tile.
// ---------------------------------------------------------------------------
__global__ __launch_bounds__(256)
void k_transpose(const float* __restrict__ dwout, float* __restrict__ dw2) {
    const int blk = blockIdx.x;            // (b*20 + t)*8 + hq
    const int hq = blk & 7;
    const int bt = blk >> 3;
    const int t  = bt % 20;
    const int b  = bt / 20;
    const int tid = threadIdx.x;
    __shared__ float lt[32][33];
    const int wsrc = tid & 31, cg = tid >> 5;    // 8 groups

    for (int hh = 0; hh < 4; ++hh) {
        const int h = hq * 4 + hh;
#pragma unroll
        for (int cc = 0; cc < 4; ++cc) {
            const int ci = cc * 8 + cg;
            lt[wsrc][ci] = dwout[((size_t)(b * 32 + ci) * TT_ + t) * NPIX + h * 32 + wsrc];
        }
        __syncthreads();
        float* drow = dw2 + ((size_t)(b * TT_ + t) * 32 + h) * NPIX;
#pragma unroll
        for (int ss = 0; ss < 4; ++ss) {
            const int slot = ss * 8 + cg;
            drow[slot * 32 + wsrc] = (slot == 0) ? 0.f : lt[slot - 1][wsrc];
        }
        __syncthreads();
    }
}

// ---------------------------------------------------------------------------
// K3: ballot-wave fused pointwise conv + recurrence.
// block = (b,h), 1024 thr = 16 waves; wave = 64 lanes = 64 co, pixel pair
// (2*wid, 2*wid+1). Per step: dwin slice (64 floats) is wave-uniform ->
// scalar loads feed v_fmac (zero LDS GEMM); spike mask = __ballot (no
// barriers in t-loop). Bitplanes in LDS; one barrier; coalesced bit->float
// store phase (full 128-B lines).
// ---------------------------------------------------------------------------
__global__ __launch_bounds__(1024, 4)
void k_recur(const float* __restrict__ dw2, const float* __restrict__ wpw,
             const float* __restrict__ dmat, const float* __restrict__ invn_g,
             const float* __restrict__ beta_g, const float* __restrict__ bvec,
             float* __restrict__ out, unsigned* __restrict__ gcnt) {
    const int b = blockIdx.x >> 5, h = blockIdx.x & 31;
    const int tid = threadIdx.x;
    const int lane = tid & 63;
    const int co = lane;
    const int wid = __builtin_amdgcn_readfirstlane(tid >> 6);   // 0..15, scalar
    const int w0 = wid * 2;

    __shared__ float d_lds[4096];
    __shared__ unsigned long long msk[NSTEP][32];

    for (int i = tid; i < 4096; i += 1024) d_lds[i] = dmat[i];
    {
        unsigned long long* mp = &msk[0][0];
        for (int i = tid; i < NSTEP * 32; i += 1024) mp[i] = 0ull;
    }

    const float beta_v = beta_g[0];
    const float omb = 1.0f - beta_v;
    const float invn = invn_g[co];
    const float bth  = bvec[co];

    float wa[32];
#pragma unroll
    for (int ci = 0; ci < 32; ++ci) wa[ci] = wpw[co * 32 + ci];

    float mem0 = 0.f, mem1 = 0.f;
    unsigned long long m0p = 0ull, m1p = 0ull;

    __syncthreads();   // d_lds + zeroed bitplanes visible

    // wave-uniform base into dw2 for (b, h-1, slots w0..w0+1); valid iff h>=1
    const int base0 = ((b * TT_) * 32 + (h - 1)) * NPIX + w0 * 32;
    const bool hok = (h >= 1);

    for (int t = 1; t < NSTEP; ++t) {
        float inp0 = 0.f, inp1 = 0.f;
        if (hok && t <= TT_) {                     // wave-uniform branch
            const float* wrow = dw2 + (size_t)base0 + (size_t)(t - 1) * (32 * NPIX);
            const f32x16 A0 = *(const f32x16*)(wrow);        // slot w0,  ci 0..15
            const f32x16 A1 = *(const f32x16*)(wrow + 16);   // slot w0,  ci 16..31
            const f32x16 A2 = *(const f32x16*)(wrow + 32);   // slot w0+1,ci 0..15
            const f32x16 A3 = *(const f32x16*)(wrow + 48);   // slot w0+1,ci 16..31
#pragma unroll
            for (int ci = 0; ci < 16; ++ci) {
                inp0 = fmaf(wa[ci], A0[ci], inp0);
                inp1 = fmaf(wa[ci], A2[ci], inp1);
            }
#pragma unroll
            for (int ci = 0; ci < 16; ++ci) {
                inp0 = fmaf(wa[16 + ci], A1[ci], inp0);
                inp1 = fmaf(wa[16 + ci], A3[ci], inp1);
            }
        }
        // lateral reset from previous step's masks (sparse, usually skipped)
        float rst0 = 0.f, rst1 = 0.f;
        unsigned long long mm = m0p;
        while (mm) { const int a = __builtin_ctzll(mm); mm &= mm - 1; rst0 += d_lds[a * 64 + co]; }
        mm = m1p;
        while (mm) { const int a = __builtin_ctzll(mm); mm &= mm - 1; rst1 += d_lds[a * 64 + co]; }

        // membrane update + spike (same expression order as validated rounds)
        const float u0 = (mem0 - rst0) * beta_v;
        mem0 = u0 + inp0 * omb;
        const bool s0 = (mem0 * invn - bth) > 0.f;
        const float u1 = (mem1 - rst1) * beta_v;
        mem1 = u1 + inp1 * omb;
        const bool s1 = (mem1 * invn - bth) > 0.f;

        m0p = __ballot(s0);
        m1p = __ballot(s1);
        if (lane == 0) { msk[t][w0] = m0p; msk[t][w0 + 1] = m1p; }
    }
    __syncthreads();

    // exact per-t spike counts (integer, deterministic)
    if (tid < NSTEP) {
        unsigned c = 0;
        for (int w = 0; w < 32; ++w) c += (unsigned)__popcll(msk[tid][w]);
        if (c) atomicAdd(&gcnt[tid], c);
    }

    // coalesced bit->float stores: 1408 (co,t) rows, 2 per wave per iter
    const int wst = lane & 31;
    const int halfsel = lane >> 5;
    for (int it = 0; it < 44; ++it) {
        const int pair = it * 32 + wid * 2 + halfsel;   // 0..1407
        const int tt = pair >> 6, cc = pair & 63;
        const unsigned long long wv = msk[tt][wst];
        const float sv = (float)((wv >> cc) & 1ull);
        out[((size_t)(b * 64 + cc) * NSTEP + tt) * NPIX + h * 32 + wst] = sv;
    }
}

// ---------------------------------------------------------------------------
// K4: losses from exact integer spike counts
// ---------------------------------------------------------------------------
__global__ void k_final(const unsigned* __restrict__ gcnt, float* __restrict__ out,
                        int out_size) {
    if (threadIdx.x == 0 && blockIdx.x == 0) {
        unsigned long long tot = 0; unsigned mx = 0;
        for (int t = 0; t < NSTEP; ++t) { const unsigned c = gcnt[t]; tot += c; if (c > mx) mx = c; }
        const long long nspk = (long long)out_size - 2;          // 23,068,672
        out[out_size - 2] = (float)(0.5 * ((double)tot / (double)nspk));
        out[out_size - 1] = (float)((double)mx / 1048576.0);     // / (B*COUT*H*W)
    }
}

extern "C" void kernel_launch(void* const* d_in, const int* in_sizes, int n_in,
                              void* d_out, int out_size, void* d_ws, size_t ws_size,
                              hipStream_t stream) {
    const float* x    = (const float*)d_in[0];
    const float* wdw  = (const float*)d_in[1];
    const float* wpw  = (const float*)d_in[2];
    const float* beta = (const float*)d_in[3];
    const float* bvec = (const float*)d_in[4];
    float* out = (float*)d_out;
    float* ws  = (float*)d_ws;

    if (ws_size < WS_FLOATS * sizeof(float)) return;

    float* dwout = ws + OFF_DWOUT;
    float* dw2   = ws + OFF_DW2;
    float* dmat  = ws + OFF_D;
    float* invn  = ws + OFF_INVN;
    unsigned* gcnt = (unsigned*)(ws + OFF_CNT);

    k_dmat     <<<1, 256, 0, stream>>>(wdw, wpw, dmat, invn, gcnt);
    k_depthwise<<<BB_ * CIN_ * 4, 128, 0, stream>>>(x, wdw, dwout);
    k_transpose<<<BB_ * TT_ * 8, 256, 0, stream>>>(dwout, dw2);
    k_recur    <<<BB_ * HW_, 1024, 0, stream>>>(dw2, wpw, dmat, invn, beta, bvec, out, gcnt);
    k_final    <<<1, 64, 0, stream>>>(gcnt, out, out_size);
}

// Round 5
// 89.720 us; speedup vs baseline: 2.3248x; 1.1077x over previous
//
#include <hip/hip_runtime.h>

// Problem constants
#define BB_   16
#define CIN_  32
#define COUT_ 64
#define TT_   20      // depthwise time extent
#define NSTEP 22      // recurrence steps (pointwise pad grows T 20->22)
#define NPIX  1024    // 32*32
#define HW_   32

typedef float f32x16 __attribute__((ext_vector_type(16)));

// ws layout (in floats)
#define N_DWOUT 10485760ULL                    // 16*32*20*1024 [ci-major]
#define N_DW2   10485760ULL                    // 16*20*32*1024 [slot][ci] transposed
#define OFF_DWOUT 0ULL
#define OFF_DW2   (OFF_DWOUT + N_DWOUT)
#define OFF_D     (OFF_DW2 + N_DW2)            // 4096 floats
#define OFF_INVN  (OFF_D + 4096ULL)            // 64 floats
#define OFF_CNT   (OFF_INVN + 64ULL)           // 22 uint32
#define WS_FLOATS (OFF_CNT + 32ULL)

// ---------------------------------------------------------------------------
// K1: depthwise 3x3x3 conv (unchanged, validated). dwout[b][ci][t][h][w]
// ---------------------------------------------------------------------------
__global__ __launch_bounds__(128)
void k_depthwise(const float* __restrict__ x, const float* __restrict__ wdw,
                 float* __restrict__ dwout) {
    const int blk = blockIdx.x;
    const int t4 = blk & 3;
    const int ci = (blk >> 2) & 31;
    const int b  = blk >> 7;
    const int tid = threadIdx.x;
    __shared__ float pl[3][34][35];

    float w[27];
#pragma unroll
    for (int k = 0; k < 27; ++k) w[k] = wdw[ci * 27 + k];

    for (int i = tid; i < 3 * 34 * 35; i += 128) (&pl[0][0][0])[i] = 0.f;
    __syncthreads();

    const float* xb = x + (size_t)(b * 32 + ci) * TT_ * NPIX;
    const int lr = tid >> 2;
    const int lc = (tid & 3) * 8;

    auto load_plane = [&](int p, int slot) {
        const float* s = xb + (size_t)p * NPIX + lr * 32 + lc;
        float4 v0 = *(const float4*)s;
        float4 v1 = *(const float4*)(s + 4);
        float* d = &pl[slot][1 + lr][1 + lc];
        d[0] = v0.x; d[1] = v0.y; d[2] = v0.z; d[3] = v0.w;
        d[4] = v1.x; d[5] = v1.y; d[6] = v1.z; d[7] = v1.w;
    };
    auto zero_plane = [&](int slot) {
        float* d = &pl[slot][1 + lr][1 + lc];
#pragma unroll
        for (int j = 0; j < 8; ++j) d[j] = 0.f;
    };

    const int T0 = t4 * 5;
    if (T0 > 0) load_plane(T0 - 1, (T0 - 1) % 3);
    load_plane(T0, T0 % 3);

    const int hd = lr, wd0 = lc;
    const float* base = &pl[0][0][0];

    for (int t = T0; t < T0 + 5; ++t) {
        __syncthreads();
        const int pnext = t + 1;
        if (pnext < TT_) load_plane(pnext, pnext % 3);
        else             zero_plane(pnext % 3);
        __syncthreads();

        const int sm1 = (t + 2) % 3, s0 = t % 3, sp1 = (t + 1) % 3;
        float acc[8] = {0.f,0.f,0.f,0.f,0.f,0.f,0.f,0.f};
#pragma unroll
        for (int kt = 0; kt < 3; ++kt) {
            const int slot = (kt == 0) ? sm1 : (kt == 1) ? s0 : sp1;
            const float* Pp = base + slot * (34 * 35);
#pragma unroll
            for (int kh = 0; kh < 3; ++kh) {
                const float* row = Pp + (hd + kh) * 35 + wd0;
                float r[10];
#pragma unroll
                for (int m = 0; m < 10; ++m) r[m] = row[m];
#pragma unroll
                for (int kw = 0; kw < 3; ++kw) {
                    const float wv = w[(kt * 3 + kh) * 3 + kw];
#pragma unroll
                    for (int j = 0; j < 8; ++j) acc[j] = fmaf(wv, r[j + kw], acc[j]);
                }
            }
        }
        float* dst = dwout + ((size_t)(b * 32 + ci) * TT_ + t) * NPIX + hd * 32 + wd0;
        *(float4*)dst       = make_float4(acc[0], acc[1], acc[2], acc[3]);
        *(float4*)(dst + 4) = make_float4(acc[4], acc[5], acc[6], acc[7]);
    }
}

// ---------------------------------------------------------------------------
// K2: lateral matrix d (fp64), inv_norm; zeros gcnt. Unchanged.
// ---------------------------------------------------------------------------
__global__ __launch_bounds__(256)
void k_dmat(const float* __restrict__ wdw, const float* __restrict__ wpw,
            float* __restrict__ dmat, float* __restrict__ invn,
            unsigned* __restrict__ gcnt) {
    __shared__ double S[32];
    const int tid = threadIdx.x;
    if (tid < NSTEP) gcnt[tid] = 0u;
    if (tid < 32) {
        double s = 0.0;
        for (int k = 0; k < 27; ++k) { double v = (double)wdw[tid * 27 + k]; s += v * v; }
        S[tid] = s;
    }
    __syncthreads();
    for (int e = tid; e < 4096; e += 256) {
        const int a = e >> 6, f = e & 63;
        double acc = 0.0;
        for (int ci = 0; ci < 32; ++ci)
            acc += (double)wpw[a * 32 + ci] * (double)wpw[f * 32 + ci] * S[ci];
        dmat[e] = (float)acc;
        if (a == f) invn[a] = (float)(1.0 / (acc + 1e-8));
    }
}

// ---------------------------------------------------------------------------
// K2b: transpose dwout -> dw2 [b][t][h][slot=w+1][ci], slot 0 = zeros.
// Unchanged, validated.
// ---------------------------------------------------------------------------
__global__ __launch_bounds__(256)
void k_transpose(const float* __restrict__ dwout, float* __restrict__ dw2) {
    const int blk = blockIdx.x;            // (b*20 + t)*8 + hq
    const int hq = blk & 7;
    const int bt = blk >> 3;
    const int t  = bt % 20;
    const int b  = bt / 20;
    const int tid = threadIdx.x;
    __shared__ float lt[32][33];
    const int wsrc = tid & 31, cg = tid >> 5;

    for (int hh = 0; hh < 4; ++hh) {
        const int h = hq * 4 + hh;
#pragma unroll
        for (int cc = 0; cc < 4; ++cc) {
            const int ci = cc * 8 + cg;
            lt[wsrc][ci] = dwout[((size_t)(b * 32 + ci) * TT_ + t) * NPIX + h * 32 + wsrc];
        }
        __syncthreads();
        float* drow = dw2 + ((size_t)(b * TT_ + t) * 32 + h) * NPIX;
#pragma unroll
        for (int ss = 0; ss < 4; ++ss) {
            const int slot = ss * 8 + cg;
            drow[slot * 32 + wsrc] = (slot == 0) ? 0.f : lt[slot - 1][wsrc];
        }
        __syncthreads();
    }
}

// ---------------------------------------------------------------------------
// K3: ballot-wave fused pointwise conv + recurrence, v2.
// block = (b, h, w-half): 1024 blocks x 512 thr (8 waves) -> 4 blocks/CU,
// store drains overlap other blocks' t-loops. Wave = 64 co for pixel pair.
// s_loads for step t+1 reissued into the SAME SGPR set right after step t's
// FMAs (loads fly during reset/ballot/mask tail; no barriers in t-loop).
// Store phase 64B-sector-exact per (co,t) row.
// ---------------------------------------------------------------------------
__global__ __launch_bounds__(512)
void k_recur(const float* __restrict__ dw2, const float* __restrict__ wpw,
             const float* __restrict__ dmat, const float* __restrict__ invn_g,
             const float* __restrict__ beta_g, const float* __restrict__ bvec,
             float* __restrict__ out, unsigned* __restrict__ gcnt) {
    const int blk = blockIdx.x;
    const int whalf = blk & 1;
    const int h = (blk >> 1) & 31;
    const int b = blk >> 6;
    const int tid = threadIdx.x;
    const int lane = tid & 63;
    const int co = lane;
    const int wid = __builtin_amdgcn_readfirstlane(tid >> 6);   // 0..7
    const int w0 = whalf * 16 + wid * 2;        // global w of wave's pixel 0

    __shared__ float d_lds[4096];
    __shared__ unsigned long long msk[NSTEP][16];

    for (int i = tid; i < 4096; i += 512) d_lds[i] = dmat[i];
    {
        unsigned long long* mp = &msk[0][0];
        for (int i = tid; i < NSTEP * 16; i += 512) mp[i] = 0ull;
    }

    const float beta_v = beta_g[0];
    const float omb = 1.0f - beta_v;
    const float invn = invn_g[co];
    const float bth  = bvec[co];

    float wa[32];
#pragma unroll
    for (int ci = 0; ci < 32; ++ci) wa[ci] = wpw[co * 32 + ci];

    float mem0 = 0.f, mem1 = 0.f;
    unsigned long long m0p = 0ull, m1p = 0ull;

    // t = 0 plane: all spikes zero (inp=0, mem=0, -b<0). 512 thr x float2 = 4KB.
    {
        const int zco = tid >> 3, zw = (tid & 7) * 2;
        *(float2*)(out + ((size_t)(b * 64 + zco) * NSTEP) * NPIX + h * 32 + whalf * 16 + zw)
            = make_float2(0.f, 0.f);
    }

    __syncthreads();   // d_lds + zeroed bitplanes visible

    // wave-uniform base into dw2 (b, h-1, slots w0..w0+1); valid iff h>=1
    const int base0 = ((b * TT_) * 32 + (h - 1)) * NPIX + w0 * 32;
    const bool hok = (h >= 1);

    f32x16 A0, A1, A2, A3;          // wave-uniform -> SGPRs
    if (hok) {                      // preload step t=1 (plane 0)
        const float* wrow = dw2 + (size_t)base0;
        A0 = *(const f32x16*)(wrow);
        A1 = *(const f32x16*)(wrow + 16);
        A2 = *(const f32x16*)(wrow + 32);
        A3 = *(const f32x16*)(wrow + 48);
    }

    for (int t = 1; t < NSTEP; ++t) {
        float inp0 = 0.f, inp1 = 0.f;
        if (hok && t <= TT_) {      // consume current A set (ci-ascending, bit-exact)
#pragma unroll
            for (int ci = 0; ci < 16; ++ci) {
                inp0 = fmaf(wa[ci], A0[ci], inp0);
                inp1 = fmaf(wa[ci], A2[ci], inp1);
            }
#pragma unroll
            for (int ci = 0; ci < 16; ++ci) {
                inp0 = fmaf(wa[16 + ci], A1[ci], inp0);
                inp1 = fmaf(wa[16 + ci], A3[ci], inp1);
            }
        }
        // reissue loads for step t+1 into the same registers (hidden under tail)
        if (hok && t < TT_) {
            const float* wrow = dw2 + (size_t)base0 + (size_t)t * (32 * NPIX);
            A0 = *(const f32x16*)(wrow);
            A1 = *(const f32x16*)(wrow + 16);
            A2 = *(const f32x16*)(wrow + 32);
            A3 = *(const f32x16*)(wrow + 48);
        }

        // lateral reset from previous step's masks (sparse bit iteration)
        float rst0 = 0.f, rst1 = 0.f;
        unsigned long long mm = m0p;
        while (mm) { const int a = __builtin_ctzll(mm); mm &= mm - 1; rst0 += d_lds[a * 64 + co]; }
        mm = m1p;
        while (mm) { const int a = __builtin_ctzll(mm); mm &= mm - 1; rst1 += d_lds[a * 64 + co]; }

        // membrane update + spike (same expression order as validated rounds)
        const float u0 = (mem0 - rst0) * beta_v;
        mem0 = u0 + inp0 * omb;
        const bool s0 = (mem0 * invn - bth) > 0.f;
        const float u1 = (mem1 - rst1) * beta_v;
        mem1 = u1 + inp1 * omb;
        const bool s1 = (mem1 * invn - bth) > 0.f;

        m0p = __ballot(s0);
        m1p = __ballot(s1);
        const int wl = wid * 2;
        if (lane == 0) { msk[t][wl] = m0p; msk[t][wl + 1] = m1p; }
    }
    __syncthreads();

    // exact per-t spike counts (integer, deterministic)
    if (tid < NSTEP) {
        unsigned c = 0;
        for (int w = 0; w < 16; ++w) c += (unsigned)__popcll(msk[tid][w]);
        if (c) atomicAdd(&gcnt[tid], c);
    }

    // coalesced bit->float stores: 1408 (co,t) rows x 16 w (64B, sector-exact)
    const int wl = tid & 15;
    for (int it = 0; it < 44; ++it) {
        const int r = it * 32 + (tid >> 4);         // 0..1407
        const int tt = r >> 6, cc = r & 63;
        const unsigned long long wv = msk[tt][wl];
        const float sv = (float)((wv >> cc) & 1ull);
        out[((size_t)(b * 64 + cc) * NSTEP + tt) * NPIX + h * 32 + whalf * 16 + wl] = sv;
    }
}

// ---------------------------------------------------------------------------
// K4: losses from exact integer spike counts
// ---------------------------------------------------------------------------
__global__ void k_final(const unsigned* __restrict__ gcnt, float* __restrict__ out,
                        int out_size) {
    if (threadIdx.x == 0 && blockIdx.x == 0) {
        unsigned long long tot = 0; unsigned mx = 0;
        for (int t = 0; t < NSTEP; ++t) { const unsigned c = gcnt[t]; tot += c; if (c > mx) mx = c; }
        const long long nspk = (long long)out_size - 2;          // 23,068,672
        out[out_size - 2] = (float)(0.5 * ((double)tot / (double)nspk));
        out[out_size - 1] = (float)((double)mx / 1048576.0);     // / (B*COUT*H*W)
    }
}

extern "C" void kernel_launch(void* const* d_in, const int* in_sizes, int n_in,
                              void* d_out, int out_size, void* d_ws, size_t ws_size,
                              hipStream_t stream) {
    const float* x    = (const float*)d_in[0];
    const float* wdw  = (const float*)d_in[1];
    const float* wpw  = (const float*)d_in[2];
    const float* beta = (const float*)d_in[3];
    const float* bvec = (const float*)d_in[4];
    float* out = (float*)d_out;
    float* ws  = (float*)d_ws;

    if (ws_size < WS_FLOATS * sizeof(float)) return;

    float* dwout = ws + OFF_DWOUT;
    float* dw2   = ws + OFF_DW2;
    float* dmat  = ws + OFF_D;
    float* invn  = ws + OFF_INVN;
    unsigned* gcnt = (unsigned*)(ws + OFF_CNT);

    k_dmat     <<<1, 256, 0, stream>>>(wdw, wpw, dmat, invn, gcnt);
    k_depthwise<<<BB_ * CIN_ * 4, 128, 0, stream>>>(x, wdw, dwout);
    k_transpose<<<BB_ * TT_ * 8, 256, 0, stream>>>(dwout, dw2);
    k_recur    <<<BB_ * HW_ * 2, 512, 0, stream>>>(dw2, wpw, dmat, invn, beta, bvec, out, gcnt);
    k_final    <<<1, 64, 0, stream>>>(gcnt, out, out_size);
}